// Round 8
// baseline (66.879 us; speedup 1.0000x reference)
//
#include <hip/hip_runtime.h>

// Problem constants: B=64, T=8192, L=64, NWIN=8128 = 8 * 1016
// Session model (R5 vs R7 system): per-launch overhead ~9.6 us, fill floor
// ~41 us. Best = ONE launch + ALL 256 CUs. Cross-block finish must avoid
// release/acquire fences (R1/R4: 512 release-fenced atomics => per-block L2
// writeback storms, ~25 us). This version uses a FENCE-FREE finish:
//   publish:  relaxed returning atomic_exchange of the packed key (serializes
//             at the coherence point, no cache maintenance)
//   order:    s_waitcnt vmcnt(0) (exchange completed before counter issues)
//   arrive:   relaxed fetch_add; 8th arriver ((old&7)==7 — exactly once per 8
//             increments for ANY initial/poison value, no ws init needed)
//   combine:  RMW-as-read (fetch_add(slot,0) — an RMW must serialize at the
//             coherence point, so it cannot read a stale L2 line; no acquire)
// Compute is round-5's proven spill-free K1 verbatim: 512 blocks x 256 thr
// (2 blocks/CU), named scalars, 4 windows/thread, j chunked by 8 (~3.8 us).
constexpr int B_SZ  = 64;
constexpr int T_SZ  = 8192;
constexpr int L_SZ  = 64;
constexpr int NWIN  = T_SZ - L_SZ;   // 8128
constexpr int NQ    = 8;             // chunks per batch -> 512 blocks
constexpr int QW    = NWIN / NQ;     // 1016 windows per chunk
constexpr int STAGE = QW + L_SZ;     // 1080 floats staged (~4.3 KB)
constexpr int NTHR  = 256;
constexpr int WPT   = 4;             // 254 active threads * 4 = 1016 windows

#define STEP(ACC, XV, YV) { const float t_ = (XV) - (YV); ACC = fmaf(t_, t_, ACC); }
#define WIN8(ACC, A,B,C,D,E,F,G,H) \
    STEP(ACC, A, y0) STEP(ACC, B, y1) STEP(ACC, C, y2) STEP(ACC, D, y3) \
    STEP(ACC, E, y4) STEP(ACC, F, y5) STEP(ACC, G, y6) STEP(ACC, H, y7)

__global__ __launch_bounds__(NTHR, 2)
void window_match_fused(const float* __restrict__ X_in,
                        const float* __restrict__ X_out,
                        unsigned long long* __restrict__ ws_keys,
                        unsigned int* __restrict__ ws_cnt,
                        float* __restrict__ out)
{
    __shared__ float xs[STAGE];                // linear float4 layout
    __shared__ float ysh[L_SZ];
    __shared__ unsigned long long wred[NTHR / 64];
    __shared__ int s_win;

    const int bq   = blockIdx.x;
    const int b    = bq >> 3;
    const int q    = bq & 7;
    const int tid  = threadIdx.x;
    const int base = q * QW;                   // 1016*q, divisible by 4

    // Stage x[b, base .. base+1079]: 270 float4 over 256 threads (coalesced).
    const float4* xg  = reinterpret_cast<const float4*>(X_in + (size_t)b * T_SZ + base);
    float4*       xs4 = reinterpret_cast<float4*>(xs);
    xs4[tid] = xg[tid];
    if (tid < STAGE / 4 - NTHR)                // 14 threads do the tail
        xs4[tid + NTHR] = xg[tid + NTHR];
    if (tid < L_SZ) ysh[tid] = X_out[(size_t)b * L_SZ + tid];
    __syncthreads();

    unsigned long long best = ~0ull;
    if (tid < QW / WPT) {                      // tid < 254
        float a0 = 0.0f, a1 = 0.0f, a2 = 0.0f, a3 = 0.0f;
        const float4* xr = reinterpret_cast<const float4*>(xs);
        const float4* yr = reinterpret_cast<const float4*>(ysh);

        // j chunked by 8: per chunk 2 broadcast y-reads + 3 stride-1 b128
        // x-reads (floats [4*tid+8jc .. +8jc+11], windows need +10).
        // Live set: 4 acc + 11 x + 8 y + addressing ~= 35 VGPRs — no spill.
        #pragma unroll
        for (int jc = 0; jc < L_SZ / 8; ++jc) {
            const float4 ya = yr[2 * jc];
            const float4 yb = yr[2 * jc + 1];
            const float y0 = ya.x, y1 = ya.y, y2 = ya.z, y3 = ya.w;
            const float y4 = yb.x, y5 = yb.y, y6 = yb.z, y7 = yb.w;

            const float4 xa = xr[tid + 2 * jc];
            const float4 xb = xr[tid + 2 * jc + 1];
            const float4 xc = xr[tid + 2 * jc + 2];
            const float x0 = xa.x, x1 = xa.y, x2  = xa.z, x3  = xa.w;
            const float x4 = xb.x, x5 = xb.y, x6  = xb.z, x7  = xb.w;
            const float x8 = xc.x, x9 = xc.y, x10 = xc.z;

            WIN8(a0, x0, x1, x2, x3, x4, x5, x6, x7)
            WIN8(a1, x1, x2, x3, x4, x5, x6, x7, x8)
            WIN8(a2, x2, x3, x4, x5, x6, x7, x8, x9)
            WIN8(a3, x3, x4, x5, x6, x7, x8, x9, x10)
        }

        // Packed key: ((float_bits(d)<<32)|idx) — d>=0 so u64 order ==
        // (dist, idx) lexicographic, ties -> smallest index == np.argmin.
        const int g0 = base + WPT * tid;
        unsigned long long k0 = ((unsigned long long)__float_as_uint(a0) << 32) | (unsigned int)(g0 + 0);
        unsigned long long k1 = ((unsigned long long)__float_as_uint(a1) << 32) | (unsigned int)(g0 + 1);
        unsigned long long k2 = ((unsigned long long)__float_as_uint(a2) << 32) | (unsigned int)(g0 + 2);
        unsigned long long k3 = ((unsigned long long)__float_as_uint(a3) << 32) | (unsigned int)(g0 + 3);
        best = k0;
        best = k1 < best ? k1 : best;
        best = k2 < best ? k2 : best;
        best = k3 < best ? k3 : best;
    }

    // Wave (64-lane) shuffle reduce, then cross-wave (4 waves) via LDS.
    #pragma unroll
    for (int off = 32; off > 0; off >>= 1) {
        const unsigned long long o = __shfl_down(best, off, 64);
        best = o < best ? o : best;
    }
    if ((tid & 63) == 0) wred[tid >> 6] = best;
    __syncthreads();

    if (tid == 0) {
        unsigned long long m = wred[0];
        m = wred[1] < m ? wred[1] : m;
        m = wred[2] < m ? wred[2] : m;
        m = wred[3] < m ? wred[3] : m;

        // --- fence-free cross-block finish (all RELAXED, agent scope) ---
        // Publish: returning exchange serializes the key at the coherence
        // point with NO cache-maintenance (unlike release, which storms L2).
        unsigned long long oldx = __hip_atomic_exchange(
            &ws_keys[bq], m, __ATOMIC_RELAXED, __HIP_MEMORY_SCOPE_AGENT);
        // Order: wait for the exchange to complete before the counter RMW.
        asm volatile("s_waitcnt vmcnt(0)" ::: "memory");
        (void)oldx;
        const unsigned int old = __hip_atomic_fetch_add(
            &ws_cnt[b], 1u, __ATOMIC_RELAXED, __HIP_MEMORY_SCOPE_AGENT);
        int sw = -1;
        if ((old & 7u) == 7u) {
            // 8th arrival => all 8 exchanges have serialized. Read the slots
            // via RMW-as-read (fetch_add 0): RMWs serialize at the coherence
            // point, so no stale-L2 read is possible without any acquire.
            unsigned long long g = ~0ull;
            #pragma unroll
            for (int qq = 0; qq < NQ; ++qq) {
                const unsigned long long v = __hip_atomic_fetch_add(
                    &ws_keys[b * NQ + qq], 0ull,
                    __ATOMIC_RELAXED, __HIP_MEMORY_SCOPE_AGENT);
                g = v < g ? v : g;
            }
            sw = (int)(g & 0xffffffffu);
        }
        s_win = sw;
    }
    __syncthreads();

    // Last-arriver block gathers: bit-exact copy of the winning window.
    const int s = s_win;
    if (s >= 0 && tid < L_SZ)
        out[(size_t)b * L_SZ + tid] = X_in[(size_t)b * T_SZ + s + tid];
}

extern "C" void kernel_launch(void* const* d_in, const int* in_sizes, int n_in,
                              void* d_out, int out_size, void* d_ws, size_t ws_size,
                              hipStream_t stream) {
    // Input order: feats_in (unused), X_in, feats_out (unused), X_out
    const float* X_in  = (const float*)d_in[1];
    const float* X_out = (const float*)d_in[3];
    float* out = (float*)d_out;
    unsigned long long* ws_keys = (unsigned long long*)d_ws;             // 512 * 8 B
    unsigned int* ws_cnt = (unsigned int*)((char*)d_ws + B_SZ * NQ * 8); // 64 * 4 B

    window_match_fused<<<B_SZ * NQ, NTHR, 0, stream>>>(X_in, X_out, ws_keys, ws_cnt, out);
}

// Round 9
// 65.121 us; speedup vs baseline: 1.0270x; 1.0270x over previous
//
#include <hip/hip_runtime.h>

// FINAL (revert-to-best): round-5 kernel verbatim — best measured (64.9 us).
// Session conclusion: three structurally disjoint variants (2-launch no-atomic,
// 1-launch 64-CU, 1-launch relaxed-atomic 256-CU) all measure 64.9-66.9 us.
// Decomposition: ~41 us unconditional harness poison-fill + ~20 us fixed
// per-iteration overhead + ~3 us device compute. Per-launch cost <=2 us.
// Kernel-side changes can move total by <5% => structural floor.
//
// K1: 512 blocks (B*NQ) x 256 thr, spill-free named-scalar inner loop
// (~35 VGPR live), stages 1080 floats in LDS, 4 windows/thread, j chunked
// by 8, block min-reduce on packed (dist,idx) u64 keys, plain store.
// K2: 64 blocks x 64 thr: min over 8 keys + gather (bit-exact input copy).
constexpr int B_SZ  = 64;
constexpr int T_SZ  = 8192;
constexpr int L_SZ  = 64;
constexpr int NWIN  = T_SZ - L_SZ;   // 8128
constexpr int NQ    = 8;             // chunks per batch -> 512 blocks
constexpr int QW    = NWIN / NQ;     // 1016 windows per chunk
constexpr int STAGE = QW + L_SZ;     // 1080 floats staged (~4.3 KB)
constexpr int NTHR  = 256;
constexpr int WPT   = 4;             // 254 active threads * 4 = 1016 windows

#define STEP(ACC, XV, YV) { const float t_ = (XV) - (YV); ACC = fmaf(t_, t_, ACC); }
#define WIN8(ACC, A,B,C,D,E,F,G,H) \
    STEP(ACC, A, y0) STEP(ACC, B, y1) STEP(ACC, C, y2) STEP(ACC, D, y3) \
    STEP(ACC, E, y4) STEP(ACC, F, y5) STEP(ACC, G, y6) STEP(ACC, H, y7)

__global__ __launch_bounds__(NTHR, 2)
void window_match_partial(const float* __restrict__ X_in,
                          const float* __restrict__ X_out,
                          unsigned long long* __restrict__ ws_keys)
{
    __shared__ float xs[STAGE];                // linear float4 layout
    __shared__ float ysh[L_SZ];
    __shared__ unsigned long long wred[NTHR / 64];

    const int bq   = blockIdx.x;
    const int b    = bq >> 3;
    const int q    = bq & 7;
    const int tid  = threadIdx.x;
    const int base = q * QW;                   // 1016*q, divisible by 4

    // Stage x[b, base .. base+1079]: 270 float4 over 256 threads (coalesced).
    const float4* xg  = reinterpret_cast<const float4*>(X_in + (size_t)b * T_SZ + base);
    float4*       xs4 = reinterpret_cast<float4*>(xs);
    xs4[tid] = xg[tid];
    if (tid < STAGE / 4 - NTHR)                // 14 threads do the tail
        xs4[tid + NTHR] = xg[tid + NTHR];
    if (tid < L_SZ) ysh[tid] = X_out[(size_t)b * L_SZ + tid];
    __syncthreads();

    unsigned long long best = ~0ull;
    if (tid < QW / WPT) {                      // tid < 254
        float a0 = 0.0f, a1 = 0.0f, a2 = 0.0f, a3 = 0.0f;
        const float4* xr = reinterpret_cast<const float4*>(xs);
        const float4* yr = reinterpret_cast<const float4*>(ysh);

        // j chunked by 8: per chunk 2 broadcast y-reads + 3 stride-1 b128
        // x-reads (floats [4*tid+8jc .. +8jc+11], windows need +10).
        // Live set: 4 acc + 11 x + 8 y + addressing ≈ 35 VGPRs — no spill.
        #pragma unroll
        for (int jc = 0; jc < L_SZ / 8; ++jc) {
            const float4 ya = yr[2 * jc];
            const float4 yb = yr[2 * jc + 1];
            const float y0 = ya.x, y1 = ya.y, y2 = ya.z, y3 = ya.w;
            const float y4 = yb.x, y5 = yb.y, y6 = yb.z, y7 = yb.w;

            const float4 xa = xr[tid + 2 * jc];
            const float4 xb = xr[tid + 2 * jc + 1];
            const float4 xc = xr[tid + 2 * jc + 2];
            const float x0 = xa.x, x1 = xa.y, x2  = xa.z, x3  = xa.w;
            const float x4 = xb.x, x5 = xb.y, x6  = xb.z, x7  = xb.w;
            const float x8 = xc.x, x9 = xc.y, x10 = xc.z;

            WIN8(a0, x0, x1, x2, x3, x4, x5, x6, x7)
            WIN8(a1, x1, x2, x3, x4, x5, x6, x7, x8)
            WIN8(a2, x2, x3, x4, x5, x6, x7, x8, x9)
            WIN8(a3, x3, x4, x5, x6, x7, x8, x9, x10)
        }

        // Packed key: ((float_bits(d)<<32)|idx) — d>=0 so u64 order ==
        // (dist, idx) lexicographic, ties -> smallest index == np.argmin.
        const int g0 = base + WPT * tid;
        unsigned long long k0 = ((unsigned long long)__float_as_uint(a0) << 32) | (unsigned int)(g0 + 0);
        unsigned long long k1 = ((unsigned long long)__float_as_uint(a1) << 32) | (unsigned int)(g0 + 1);
        unsigned long long k2 = ((unsigned long long)__float_as_uint(a2) << 32) | (unsigned int)(g0 + 2);
        unsigned long long k3 = ((unsigned long long)__float_as_uint(a3) << 32) | (unsigned int)(g0 + 3);
        best = k0;
        best = k1 < best ? k1 : best;
        best = k2 < best ? k2 : best;
        best = k3 < best ? k3 : best;
    }

    // Wave (64-lane) shuffle reduce, then cross-wave (4 waves) via LDS.
    #pragma unroll
    for (int off = 32; off > 0; off >>= 1) {
        const unsigned long long o = __shfl_down(best, off, 64);
        best = o < best ? o : best;
    }
    if ((tid & 63) == 0) wred[tid >> 6] = best;
    __syncthreads();

    if (tid == 0) {
        unsigned long long m = wred[0];
        m = wred[1] < m ? wred[1] : m;
        m = wred[2] < m ? wred[2] : m;
        m = wred[3] < m ? wred[3] : m;
        ws_keys[bq] = m;                       // plain store; kernel-end flush
    }
}

// K2: 64 blocks x 64 threads. All threads redundantly min-reduce the batch's
// 8 keys (broadcast loads, no sync) and copy the winning 64-float window.
__global__ __launch_bounds__(64)
void window_match_gather(const float* __restrict__ X_in,
                         const unsigned long long* __restrict__ ws_keys,
                         float* __restrict__ out)
{
    const int b   = blockIdx.x;
    const int tid = threadIdx.x;

    unsigned long long m = ws_keys[b * NQ + 0];
    #pragma unroll
    for (int qq = 1; qq < NQ; ++qq) {
        const unsigned long long o = ws_keys[b * NQ + qq];
        m = o < m ? o : m;
    }
    const int s = (int)(m & 0xffffffffu);
    out[(size_t)b * L_SZ + tid] = X_in[(size_t)b * T_SZ + s + tid];
}

extern "C" void kernel_launch(void* const* d_in, const int* in_sizes, int n_in,
                              void* d_out, int out_size, void* d_ws, size_t ws_size,
                              hipStream_t stream) {
    // Input order: feats_in (unused), X_in, feats_out (unused), X_out
    const float* X_in  = (const float*)d_in[1];
    const float* X_out = (const float*)d_in[3];
    float* out = (float*)d_out;
    unsigned long long* ws_keys = (unsigned long long*)d_ws;   // 512 * 8 B

    window_match_partial<<<B_SZ * NQ, NTHR, 0, stream>>>(X_in, X_out, ws_keys);
    window_match_gather<<<B_SZ, 64, 0, stream>>>(X_in, ws_keys, out);
}